// Round 7
// baseline (264.471 us; speedup 1.0000x reference)
//
#include <hip/hip_runtime.h>
#include <hip/hip_bf16.h>

#define GLOBAL_AS __attribute__((address_space(1)))
#define LDS_AS    __attribute__((address_space(3)))

typedef __bf16 bf16x8 __attribute__((ext_vector_type(8)));
typedef float  f32x4  __attribute__((ext_vector_type(4)));

constexpr int BATCH = 8192;           // M
constexpr int IN    = 1024;
constexpr int OUT   = 1024;           // N
constexpr int KDIM  = IN * 4;         // 4096 (4 "powers" per input)
constexpr int TM = 128, TN = 256, BK = 32;
constexpr int NKT = KDIM / BK;        // 128 K-iterations

// round-to-nearest-even float -> bf16 bits (inputs finite)
__device__ __forceinline__ unsigned short f2bf(float f) {
    union { float f; unsigned u; } v; v.f = f;
    unsigned r = v.u + 0x7fffu + ((v.u >> 16) & 1u);
    return (unsigned short)(r >> 16);
}
__device__ __forceinline__ unsigned pk(unsigned short a, unsigned short b) {
    return (unsigned)a | ((unsigned)b << 16);
}

// Merged prep: blocks [0,8192) build A_big; blocks [8192,9216) build B_big + be.
// A_big[b, 4i+k] = {silu(x), x, x^2, x^3} bf16.
// B_big[o, 4i+k] = {W[o,i], C[o,i,1..3]} bf16; be[o] = bias[o] + sum_i C[o,i,0].
__global__ __launch_bounds__(256) void prep(const float* __restrict__ x,
                                            const float* __restrict__ W,
                                            const float* __restrict__ C,
                                            const float* __restrict__ bias,
                                            unsigned short* __restrict__ Ab,
                                            unsigned short* __restrict__ Bb,
                                            float* __restrict__ be) {
    if (blockIdx.x < 8192) {
        int idx = blockIdx.x * 256 + threadIdx.x;      // 8192*1024/4 threads
        float4 v = reinterpret_cast<const float4*>(x)[idx];
        float e0[4] = {v.x, v.y, v.z, v.w};
        unsigned short o[16];
#pragma unroll
        for (int j = 0; j < 4; ++j) {
            float xv = e0[j];
            // silu via fast rcp (error ~1 ulp fp32, invisible after bf16 round)
            float s  = xv * __builtin_amdgcn_rcpf(1.0f + __expf(-xv));
            float x2 = xv * xv;
            o[4*j+0] = f2bf(s);
            o[4*j+1] = f2bf(xv);
            o[4*j+2] = f2bf(x2);
            o[4*j+3] = f2bf(x2 * xv);
        }
        uint4 d0 = make_uint4(pk(o[0],o[1]), pk(o[2],o[3]),   pk(o[4],o[5]),   pk(o[6],o[7]));
        uint4 d1 = make_uint4(pk(o[8],o[9]), pk(o[10],o[11]), pk(o[12],o[13]), pk(o[14],o[15]));
        uint4* dst = reinterpret_cast<uint4*>(Ab) + (size_t)idx * 2;
        dst[0] = d0;
        dst[1] = d1;
    } else {
        const int o = blockIdx.x - 8192, t = threadIdx.x;
        const int i0 = t * 4;
        const float4* c4 = reinterpret_cast<const float4*>(C + ((size_t)o * IN + i0) * 4);
        float4 w4 = *reinterpret_cast<const float4*>(W + (size_t)o * IN + i0);
        float wv[4] = {w4.x, w4.y, w4.z, w4.w};
        float s = 0.f;
        unsigned d[8];
#pragma unroll
        for (int j = 0; j < 4; ++j) {
            float4 c = c4[j];
            s += c.x;                                  // x^0 term -> bias
            d[2*j]   = pk(f2bf(wv[j]), f2bf(c.y));
            d[2*j+1] = pk(f2bf(c.z),   f2bf(c.w));
        }
        uint4* dst = reinterpret_cast<uint4*>(Bb + (size_t)o * KDIM + i0 * 4);
        dst[0] = make_uint4(d[0], d[1], d[2], d[3]);
        dst[1] = make_uint4(d[4], d[5], d[6], d[7]);
#pragma unroll
        for (int off = 32; off > 0; off >>= 1) s += __shfl_down(s, off, 64);
        __shared__ float red[4];
        if ((t & 63) == 0) red[t >> 6] = s;
        __syncthreads();
        if (t == 0) be[o] = bias[o] + red[0] + red[1] + red[2] + red[3];
    }
}

// C = A_big(8192x4096) * B_big(1024x4096)^T + be.
// FAT-WAVE config: 128x256 block, 4 waves of 64x128 each, BK=32, dbuf LDS with
// one barrier per K-iter (R5 structure). Grid 256 = 1 block/CU, 1 wave/SIMD:
// latency hidden by ILP (32 independent MFMAs per iter), not TLP.
// LDS XOR-swizzle identical to R3/R5 (measured 0 conflicts). XCD-aware remap.
__global__ __launch_bounds__(256, 1) void gemm_kan(
        const unsigned short* __restrict__ Ab,
        const unsigned short* __restrict__ Bb,
        const float* __restrict__ be,
        float* __restrict__ out) {
    __shared__ unsigned short sA[2][TM * BK];   // 2 x 8 KB
    __shared__ unsigned short sB[2][TN * BK];   // 2 x 16 KB  (48 KB total)

    const int t   = threadIdx.x;
    const int l   = blockIdx.x;              // 0..255
    const int bm  = (l & 7) * 8 + ((l >> 3) & 7);   // XCD (l&7) owns bm 8x..8x+7
    const int bn  = l >> 6;                  // 0..3
    const int lane = t & 63;
    const int wave = t >> 6;
    const int wr   = wave >> 1;              // 64-row half of TM=128
    const int wc   = wave & 1;               // 128-col half of TN=256
    const int l15  = lane & 15;
    const int quad = lane >> 4;

    // staging (R3-verified): thread t -> row = t>>2, kgroup = (t&3)^((t>>3)&3), dst = t*16B
    const int rowS = t >> 2;                 // 0..63 (rows per 4KB pass)
    const int colS = ((t & 3) ^ ((t >> 3) & 3)) * 8;

    const unsigned short* pa[2];
    const unsigned short* pb[4];
#pragma unroll
    for (int i = 0; i < 2; ++i)
        pa[i] = Ab + (size_t)(bm * TM + i * 64 + rowS) * KDIM + colS;
#pragma unroll
    for (int i = 0; i < 4; ++i)
        pb[i] = Bb + (size_t)(bn * TN + i * 64 + rowS) * KDIM + colS;

    f32x4 acc[4][8];
    const f32x4 zero = {0.f, 0.f, 0.f, 0.f};
#pragma unroll
    for (int i = 0; i < 4; ++i)
#pragma unroll
        for (int j = 0; j < 8; ++j) acc[i][j] = zero;

    // read slot (R3-verified): xq = (quad ^ ((row>>1)&3))*8, row = 16m + l15
    const int xq   = (quad ^ ((l15 >> 1) & 3)) * 8;
    const int aoff = (wr * 64 + l15) * BK + xq;    // + mi*16*BK
    const int boff = (wc * 128 + l15) * BK + xq;   // + ni*16*BK

    // prologue: stage tile 0 into buffer 0
#pragma unroll
    for (int i = 0; i < 2; ++i)
        __builtin_amdgcn_global_load_lds((const GLOBAL_AS void*)pa[i],
                                         (LDS_AS void*)(sA[0] + i * 2048 + t * 8), 16, 0, 0);
#pragma unroll
    for (int i = 0; i < 4; ++i)
        __builtin_amdgcn_global_load_lds((const GLOBAL_AS void*)pb[i],
                                         (LDS_AS void*)(sB[0] + i * 2048 + t * 8), 16, 0, 0);

    for (int kt = 0; kt < NKT; ++kt) {
        __syncthreads();   // tile kt staged (its loads were issued one iter ago)

        if (kt + 1 < NKT) {
            const int koff = (kt + 1) * BK;
            const int nb = (kt + 1) & 1;
#pragma unroll
            for (int i = 0; i < 2; ++i)
                __builtin_amdgcn_global_load_lds((const GLOBAL_AS void*)(pa[i] + koff),
                                                 (LDS_AS void*)(sA[nb] + i * 2048 + t * 8), 16, 0, 0);
#pragma unroll
            for (int i = 0; i < 4; ++i)
                __builtin_amdgcn_global_load_lds((const GLOBAL_AS void*)(pb[i] + koff),
                                                 (LDS_AS void*)(sB[nb] + i * 2048 + t * 8), 16, 0, 0);
        }

        const unsigned short* a_base = sA[kt & 1];
        const unsigned short* b_base = sB[kt & 1];
        bf16x8 af[4], bv[8];
#pragma unroll
        for (int mi = 0; mi < 4; ++mi)
            af[mi] = *reinterpret_cast<const bf16x8*>(a_base + aoff + mi * 16 * BK);
#pragma unroll
        for (int ni = 0; ni < 8; ++ni)
            bv[ni] = *reinterpret_cast<const bf16x8*>(b_base + boff + ni * 16 * BK);

#pragma unroll
        for (int mi = 0; mi < 4; ++mi)
#pragma unroll
            for (int ni = 0; ni < 8; ++ni)
                acc[mi][ni] = __builtin_amdgcn_mfma_f32_16x16x32_bf16(
                    af[mi], bv[ni], acc[mi][ni], 0, 0, 0);
    }

    // epilogue: C/D layout col = lane&15, row = quad*4 + reg
    float bev[8];
#pragma unroll
    for (int ni = 0; ni < 8; ++ni)
        bev[ni] = be[bn * TN + wc * 128 + ni * 16 + l15];

#pragma unroll
    for (int mi = 0; mi < 4; ++mi) {
        const int grow = bm * TM + wr * 64 + mi * 16 + quad * 4;
#pragma unroll
        for (int ni = 0; ni < 8; ++ni) {
            const int gcol = bn * TN + wc * 128 + ni * 16 + l15;
            float* po = out + (size_t)grow * OUT + gcol;
#pragma unroll
            for (int r = 0; r < 4; ++r)
                po[(size_t)r * OUT] = acc[mi][ni][r] + bev[ni];
        }
    }
}

extern "C" void kernel_launch(void* const* d_in, const int* in_sizes, int n_in,
                              void* d_out, int out_size, void* d_ws, size_t ws_size,
                              hipStream_t stream) {
    const float* x    = (const float*)d_in[0];   // [8192,1024]
    const float* W    = (const float*)d_in[1];   // [1024,1024]
    const float* C    = (const float*)d_in[2];   // [1024,1024,4]
    const float* bias = (const float*)d_in[3];   // [1024]
    float* out = (float*)d_out;

    unsigned short* Ab = (unsigned short*)d_ws;                    // 64 MB
    unsigned short* Bb = Ab + (size_t)BATCH * KDIM;                // 8 MB
    float*          be = (float*)(Bb + (size_t)OUT * KDIM);        // 4 KB

    prep<<<dim3(8192 + 1024), dim3(256), 0, stream>>>(x, W, C, bias, Ab, Bb, be);

    gemm_kan<<<dim3(256), dim3(256), 0, stream>>>(Ab, Bb, be, out);
}

// Round 8
// 181.498 us; speedup vs baseline: 1.4572x; 1.4572x over previous
//
#include <hip/hip_runtime.h>
#include <hip/hip_bf16.h>

#define GLOBAL_AS __attribute__((address_space(1)))
#define LDS_AS    __attribute__((address_space(3)))

typedef __bf16 bf16x8 __attribute__((ext_vector_type(8)));
typedef float  f32x4  __attribute__((ext_vector_type(4)));

constexpr int BATCH = 8192;           // M
constexpr int IN    = 1024;
constexpr int OUT   = 1024;           // N
constexpr int KDIM  = IN * 4;         // 4096 (4 "powers" per input)
constexpr int TM = 128, TN = 128, BK = 64;
constexpr int NKT = KDIM / BK;        // 64 K-iterations

// round-to-nearest-even float -> bf16 bits (inputs finite)
__device__ __forceinline__ unsigned short f2bf(float f) {
    union { float f; unsigned u; } v; v.f = f;
    unsigned r = v.u + 0x7fffu + ((v.u >> 16) & 1u);
    return (unsigned short)(r >> 16);
}
__device__ __forceinline__ unsigned pk(unsigned short a, unsigned short b) {
    return (unsigned)a | ((unsigned)b << 16);
}
__device__ __forceinline__ unsigned pk2f(float a, float b) {
    return pk(f2bf(a), f2bf(b));
}

// prep: B_big[o, 4i+k] = {W[o,i], C[o,i,1..3]} bf16; be[o] = bias[o] + sum_i C[o,i,0].
__global__ __launch_bounds__(256) void prep_w(const float* __restrict__ W,
                                              const float* __restrict__ C,
                                              const float* __restrict__ bias,
                                              unsigned short* __restrict__ Bb,
                                              float* __restrict__ be) {
    const int o = blockIdx.x, t = threadIdx.x;
    const int i0 = t * 4;
    const float4* c4 = reinterpret_cast<const float4*>(C + ((size_t)o * IN + i0) * 4);
    float4 w4 = *reinterpret_cast<const float4*>(W + (size_t)o * IN + i0);
    float wv[4] = {w4.x, w4.y, w4.z, w4.w};
    float s = 0.f;
    unsigned d[8];
#pragma unroll
    for (int j = 0; j < 4; ++j) {
        float4 c = c4[j];
        s += c.x;                                  // x^0 term -> bias
        d[2*j]   = pk2f(wv[j], c.y);
        d[2*j+1] = pk2f(c.z,   c.w);
    }
    uint4* dst = reinterpret_cast<uint4*>(Bb + (size_t)o * KDIM + i0 * 4);
    dst[0] = make_uint4(d[0], d[1], d[2], d[3]);
    dst[1] = make_uint4(d[4], d[5], d[6], d[7]);
#pragma unroll
    for (int off = 32; off > 0; off >>= 1) s += __shfl_down(s, off, 64);
    __shared__ float red[4];
    if ((t & 63) == 0) red[t >> 6] = s;
    __syncthreads();
    if (t == 0) be[o] = bias[o] + red[0] + red[1] + red[2] + red[3];
}

// out = [silu(x),x,x^2,x^3](8192x4096) * B_big(1024x4096)^T + be.
// R5 structure (128x128, BK=64, dbuf, one barrier/iter, 64x64 waves, 2 blk/CU)
// with the A-expansion FUSED and PIPELINED: thread register-prefetches its 8 raw
// x floats one iter ahead, expands to 32 bf16 during iter n into Ab2[(n+1)&1]
// (ds_write_b128, swizzled), while MFMA consumes Ab2[n&1]. A_big never hits HBM.
// LDS = 2*16 (A) + 2*16 (B) = 64 KB. XOR swizzle slot = kgroup ^ (row&7) (R5,
// 0 conflicts measured). XCD-aware remap.
__global__ __launch_bounds__(256, 2) void gemm_kan(
        const float* __restrict__ x,
        const unsigned short* __restrict__ Bb,
        const float* __restrict__ be,
        float* __restrict__ out) {
    __shared__ unsigned short sA[2][TM * BK];   // 2 x 16 KB
    __shared__ unsigned short sB[2][TN * BK];   // 2 x 16 KB

    const int t   = threadIdx.x;
    const int l   = blockIdx.x;              // 0..511
    const int bm  = (l & 7) * 8 + ((l >> 3) & 7);   // XCD (l&7) owns bm 8x..8x+7
    const int bn  = l >> 6;                  // 0..7
    const int lane = t & 63;
    const int wave = t >> 6;
    const int wr   = wave >> 1;              // 64-row half
    const int wc   = wave & 1;               // 64-col half
    const int l15  = lane & 15;
    const int quad = lane >> 4;

    // ---- A expansion mapping: thread t owns row rA = t>>1, x-half hA = t&1
    //      (8 x-values per iter -> 4 k-groups 4hA..4hA+3 -> 4 swizzled b128 writes)
    const int rA = t >> 1;
    const int hA = t & 1;
    const float* pxt = x + (size_t)(bm * TM + rA) * IN + hA * 8;
    unsigned aw[4];   // byte offsets of the 4 swizzled write slots in a row
#pragma unroll
    for (int jj = 0; jj < 4; ++jj)
        aw[jj] = rA * (BK * 2) + (((4 * hA + jj) ^ (rA & 7)) * 16);

    // ---- B staging (R5-verified): row = i*32 + (t>>3), slot = t&7, src kgroup = slot^(row&7)
    const int rowT = t >> 3;                  // 0..31
    const int gT   = (t & 7) ^ (rowT & 7);
    const unsigned short* pb[4];
#pragma unroll
    for (int i = 0; i < 4; ++i)
        pb[i] = Bb + (size_t)(bn * TN + i * 32 + rowT) * KDIM + gT * 8;

    f32x4 acc[4][4];
    const f32x4 zero = {0.f, 0.f, 0.f, 0.f};
#pragma unroll
    for (int i = 0; i < 4; ++i)
#pragma unroll
        for (int j = 0; j < 4; ++j) acc[i][j] = zero;

    const int xr = l15 & 7;                   // row&7 for fragment rows (16m + l15)

    // ---- prologue ----
    // x chunk 0 -> regs
    float4 x0a = *reinterpret_cast<const float4*>(pxt);
    float4 x0b = *reinterpret_cast<const float4*>(pxt + 4);
    // B chunk 0 -> Bb buffer 0
#pragma unroll
    for (int i = 0; i < 4; ++i)
        __builtin_amdgcn_global_load_lds((const GLOBAL_AS void*)pb[i],
                                         (LDS_AS void*)(sB[0] + i * 2048 + t * 8), 16, 0, 0);
    // expand chunk 0 -> Ab buffer 0
    {
        float xs[8] = {x0a.x, x0a.y, x0a.z, x0a.w, x0b.x, x0b.y, x0b.z, x0b.w};
#pragma unroll
        for (int jj = 0; jj < 4; ++jj) {
            float u = xs[2*jj], v = xs[2*jj+1];
            float su = u * __builtin_amdgcn_rcpf(1.0f + __expf(-u));
            float sv = v * __builtin_amdgcn_rcpf(1.0f + __expf(-v));
            float u2 = u * u, v2 = v * v;
            uint4 d = make_uint4(pk2f(su, u), pk2f(u2, u2 * u),
                                 pk2f(sv, v), pk2f(v2, v2 * v));
            *reinterpret_cast<uint4*>(reinterpret_cast<char*>(sA[0]) + aw[jj]) = d;
        }
    }
    // x chunk 1 -> regs
    float4 xna = *reinterpret_cast<const float4*>(pxt + 16);
    float4 xnb = *reinterpret_cast<const float4*>(pxt + 20);

    for (int kt = 0; kt < NKT; ++kt) {
        __syncthreads();   // buffers kt ready (B loads + A expansion from iter kt-1)

        const int nb = (kt + 1) & 1;
        if (kt + 1 < NKT) {
            const int koff = (kt + 1) * BK;
            // issue B chunk kt+1
#pragma unroll
            for (int i = 0; i < 4; ++i)
                __builtin_amdgcn_global_load_lds((const GLOBAL_AS void*)(pb[i] + koff),
                                                 (LDS_AS void*)(sB[nb] + i * 2048 + t * 8), 16, 0, 0);
            // expand x chunk kt+1 (regs prefetched during iter kt-1) -> Ab[nb]
            float xs[8] = {xna.x, xna.y, xna.z, xna.w, xnb.x, xnb.y, xnb.z, xnb.w};
#pragma unroll
            for (int jj = 0; jj < 4; ++jj) {
                float u = xs[2*jj], v = xs[2*jj+1];
                float su = u * __builtin_amdgcn_rcpf(1.0f + __expf(-u));
                float sv = v * __builtin_amdgcn_rcpf(1.0f + __expf(-v));
                float u2 = u * u, v2 = v * v;
                uint4 d = make_uint4(pk2f(su, u), pk2f(u2, u2 * u),
                                     pk2f(sv, v), pk2f(v2, v2 * v));
                *reinterpret_cast<uint4*>(reinterpret_cast<char*>(sA[nb]) + aw[jj]) = d;
            }
            // prefetch x chunk kt+2
            if (kt + 2 < NKT) {
                xna = *reinterpret_cast<const float4*>(pxt + (kt + 2) * 16);
                xnb = *reinterpret_cast<const float4*>(pxt + (kt + 2) * 16 + 4);
            }
        }

        const unsigned short* a_base = sA[kt & 1];
        const unsigned short* b_base = sB[kt & 1];
#pragma unroll
        for (int kk = 0; kk < 2; ++kk) {
            const int cq = ((kk * 4 + quad) ^ xr) * 8;
            bf16x8 af[4], bv[4];
#pragma unroll
            for (int mi = 0; mi < 4; ++mi)
                af[mi] = *reinterpret_cast<const bf16x8*>(
                    a_base + (wr * 64 + mi * 16 + l15) * BK + cq);
#pragma unroll
            for (int ni = 0; ni < 4; ++ni)
                bv[ni] = *reinterpret_cast<const bf16x8*>(
                    b_base + (wc * 64 + ni * 16 + l15) * BK + cq);
#pragma unroll
            for (int mi = 0; mi < 4; ++mi)
#pragma unroll
                for (int ni = 0; ni < 4; ++ni)
                    acc[mi][ni] = __builtin_amdgcn_mfma_f32_16x16x32_bf16(
                        af[mi], bv[ni], acc[mi][ni], 0, 0, 0);
        }
    }

    // epilogue: C/D layout col = lane&15, row = quad*4 + reg
    float bev[4];
#pragma unroll
    for (int ni = 0; ni < 4; ++ni)
        bev[ni] = be[bn * TN + wc * 64 + ni * 16 + l15];

#pragma unroll
    for (int mi = 0; mi < 4; ++mi) {
        const int grow = bm * TM + wr * 64 + mi * 16 + quad * 4;
#pragma unroll
        for (int ni = 0; ni < 4; ++ni) {
            const int gcol = bn * TN + wc * 64 + ni * 16 + l15;
            float* po = out + (size_t)grow * OUT + gcol;
#pragma unroll
            for (int r = 0; r < 4; ++r)
                po[(size_t)r * OUT] = acc[mi][ni][r] + bev[ni];
        }
    }
}

extern "C" void kernel_launch(void* const* d_in, const int* in_sizes, int n_in,
                              void* d_out, int out_size, void* d_ws, size_t ws_size,
                              hipStream_t stream) {
    const float* x    = (const float*)d_in[0];   // [8192,1024]
    const float* W    = (const float*)d_in[1];   // [1024,1024]
    const float* C    = (const float*)d_in[2];   // [1024,1024,4]
    const float* bias = (const float*)d_in[3];   // [1024]
    float* out = (float*)d_out;

    unsigned short* Bb = (unsigned short*)d_ws;             // 8 MB
    float*          be = (float*)(Bb + (size_t)OUT * KDIM); // 4 KB

    prep_w<<<dim3(OUT), dim3(256), 0, stream>>>(W, C, bias, Bb, be);

    gemm_kan<<<dim3(512), dim3(256), 0, stream>>>(x, Bb, be, out);
}

// Round 9
// 177.868 us; speedup vs baseline: 1.4869x; 1.0204x over previous
//
#include <hip/hip_runtime.h>
#include <hip/hip_bf16.h>

#define GLOBAL_AS __attribute__((address_space(1)))
#define LDS_AS    __attribute__((address_space(3)))

typedef __bf16 bf16x8 __attribute__((ext_vector_type(8)));
typedef float  f32x4  __attribute__((ext_vector_type(4)));

constexpr int BATCH = 8192;           // M
constexpr int IN    = 1024;
constexpr int OUT   = 1024;           // N
constexpr int KDIM  = IN * 4;         // 4096 (4 "powers" per input)
constexpr int TM = 128, TN = 128, BK = 64;
constexpr int NKT = KDIM / BK;        // 64 K-iterations

// packed f32x2 -> bf16x2 (RNE) via v_cvt_pk_bf16_f32 on gfx950; a in low half.
__device__ __forceinline__ unsigned pk2f(float a, float b) {
    __hip_bfloat162 h = __float22bfloat162_rn(make_float2(a, b));
    return *reinterpret_cast<unsigned*>(&h);
}

// prep: B_big[o, 4i+k] = {W[o,i], C[o,i,1..3]} bf16; be[o] = bias[o] + sum_i C[o,i,0].
__global__ __launch_bounds__(256) void prep_w(const float* __restrict__ W,
                                              const float* __restrict__ C,
                                              const float* __restrict__ bias,
                                              unsigned short* __restrict__ Bb,
                                              float* __restrict__ be) {
    const int o = blockIdx.x, t = threadIdx.x;
    const int i0 = t * 4;
    const float4* c4 = reinterpret_cast<const float4*>(C + ((size_t)o * IN + i0) * 4);
    float4 w4 = *reinterpret_cast<const float4*>(W + (size_t)o * IN + i0);
    float wv[4] = {w4.x, w4.y, w4.z, w4.w};
    float s = 0.f;
    unsigned d[8];
#pragma unroll
    for (int j = 0; j < 4; ++j) {
        float4 c = c4[j];
        s += c.x;                                  // x^0 term -> bias
        d[2*j]   = pk2f(wv[j], c.y);
        d[2*j+1] = pk2f(c.z,   c.w);
    }
    uint4* dst = reinterpret_cast<uint4*>(Bb + (size_t)o * KDIM + i0 * 4);
    dst[0] = make_uint4(d[0], d[1], d[2], d[3]);
    dst[1] = make_uint4(d[4], d[5], d[6], d[7]);
#pragma unroll
    for (int off = 32; off > 0; off >>= 1) s += __shfl_down(s, off, 64);
    __shared__ float red[4];
    if ((t & 63) == 0) red[t >> 6] = s;
    __syncthreads();
    if (t == 0) be[o] = bias[o] + red[0] + red[1] + red[2] + red[3];
}

// out = [silu(x),x,x^2,x^3](8192x4096) * B_big(1024x4096)^T + be.
// R5 structure (128x128, BK=64, dbuf, one barrier/iter, 64x64 waves, 2 blk/CU)
// with fused pipelined A-expansion (R8) using HW v_cvt_pk_bf16_f32 packing.
// LDS = 64 KB. XOR swizzle slot = kgroup ^ (row&7) (0 conflicts measured).
__global__ __launch_bounds__(256, 2) void gemm_kan(
        const float* __restrict__ x,
        const unsigned short* __restrict__ Bb,
        const float* __restrict__ be,
        float* __restrict__ out) {
    __shared__ unsigned short sA[2][TM * BK];   // 2 x 16 KB
    __shared__ unsigned short sB[2][TN * BK];   // 2 x 16 KB

    const int t   = threadIdx.x;
    const int l   = blockIdx.x;              // 0..511
    const int bm  = (l & 7) * 8 + ((l >> 3) & 7);   // XCD (l&7) owns bm 8x..8x+7
    const int bn  = l >> 6;                  // 0..7
    const int lane = t & 63;
    const int wave = t >> 6;
    const int wr   = wave >> 1;              // 64-row half
    const int wc   = wave & 1;               // 64-col half
    const int l15  = lane & 15;
    const int quad = lane >> 4;

    // ---- A expansion mapping: thread t owns row rA = t>>1, x-half hA = t&1
    const int rA = t >> 1;
    const int hA = t & 1;
    const float* pxt = x + (size_t)(bm * TM + rA) * IN + hA * 8;
    unsigned aw[4];   // byte offsets of the 4 swizzled b128 write slots
#pragma unroll
    for (int jj = 0; jj < 4; ++jj)
        aw[jj] = rA * (BK * 2) + (((4 * hA + jj) ^ (rA & 7)) * 16);

    // ---- B staging (R5-verified): row = i*32 + (t>>3), slot = t&7, src kgroup = slot^(row&7)
    const int rowT = t >> 3;                  // 0..31
    const int gT   = (t & 7) ^ (rowT & 7);
    const unsigned short* pb[4];
#pragma unroll
    for (int i = 0; i < 4; ++i)
        pb[i] = Bb + (size_t)(bn * TN + i * 32 + rowT) * KDIM + gT * 8;

    f32x4 acc[4][4];
    const f32x4 zero = {0.f, 0.f, 0.f, 0.f};
#pragma unroll
    for (int i = 0; i < 4; ++i)
#pragma unroll
        for (int j = 0; j < 4; ++j) acc[i][j] = zero;

    const int xr = l15 & 7;                   // row&7 for fragment rows (16m + l15)

    // ---- prologue ----
    float4 x0a = *reinterpret_cast<const float4*>(pxt);
    float4 x0b = *reinterpret_cast<const float4*>(pxt + 4);
#pragma unroll
    for (int i = 0; i < 4; ++i)
        __builtin_amdgcn_global_load_lds((const GLOBAL_AS void*)pb[i],
                                         (LDS_AS void*)(sB[0] + i * 2048 + t * 8), 16, 0, 0);
    {
        float xs[8] = {x0a.x, x0a.y, x0a.z, x0a.w, x0b.x, x0b.y, x0b.z, x0b.w};
#pragma unroll
        for (int jj = 0; jj < 4; ++jj) {
            float u = xs[2*jj], v = xs[2*jj+1];
            float su = u * __builtin_amdgcn_rcpf(1.0f + __expf(-u));
            float sv = v * __builtin_amdgcn_rcpf(1.0f + __expf(-v));
            float u2 = u * u, v2 = v * v;
            uint4 d = make_uint4(pk2f(su, u), pk2f(u2, u2 * u),
                                 pk2f(sv, v), pk2f(v2, v2 * v));
            *reinterpret_cast<uint4*>(reinterpret_cast<char*>(sA[0]) + aw[jj]) = d;
        }
    }
    float4 xna = *reinterpret_cast<const float4*>(pxt + 16);
    float4 xnb = *reinterpret_cast<const float4*>(pxt + 20);

    for (int kt = 0; kt < NKT; ++kt) {
        __syncthreads();   // buffers kt ready (B DMA + A expansion from iter kt-1)

        const int nb = (kt + 1) & 1;
        if (kt + 1 < NKT) {
            const int koff = (kt + 1) * BK;
#pragma unroll
            for (int i = 0; i < 4; ++i)
                __builtin_amdgcn_global_load_lds((const GLOBAL_AS void*)(pb[i] + koff),
                                                 (LDS_AS void*)(sB[nb] + i * 2048 + t * 8), 16, 0, 0);
            float xs[8] = {xna.x, xna.y, xna.z, xna.w, xnb.x, xnb.y, xnb.z, xnb.w};
#pragma unroll
            for (int jj = 0; jj < 4; ++jj) {
                float u = xs[2*jj], v = xs[2*jj+1];
                float su = u * __builtin_amdgcn_rcpf(1.0f + __expf(-u));
                float sv = v * __builtin_amdgcn_rcpf(1.0f + __expf(-v));
                float u2 = u * u, v2 = v * v;
                uint4 d = make_uint4(pk2f(su, u), pk2f(u2, u2 * u),
                                     pk2f(sv, v), pk2f(v2, v2 * v));
                *reinterpret_cast<uint4*>(reinterpret_cast<char*>(sA[nb]) + aw[jj]) = d;
            }
            if (kt + 2 < NKT) {
                xna = *reinterpret_cast<const float4*>(pxt + (kt + 2) * 16);
                xnb = *reinterpret_cast<const float4*>(pxt + (kt + 2) * 16 + 4);
            }
        }

        const unsigned short* a_base = sA[kt & 1];
        const unsigned short* b_base = sB[kt & 1];
#pragma unroll
        for (int kk = 0; kk < 2; ++kk) {
            const int cq = ((kk * 4 + quad) ^ xr) * 8;
            bf16x8 af[4], bv[4];
#pragma unroll
            for (int mi = 0; mi < 4; ++mi)
                af[mi] = *reinterpret_cast<const bf16x8*>(
                    a_base + (wr * 64 + mi * 16 + l15) * BK + cq);
#pragma unroll
            for (int ni = 0; ni < 4; ++ni)
                bv[ni] = *reinterpret_cast<const bf16x8*>(
                    b_base + (wc * 64 + ni * 16 + l15) * BK + cq);
#pragma unroll
            for (int mi = 0; mi < 4; ++mi)
#pragma unroll
                for (int ni = 0; ni < 4; ++ni)
                    acc[mi][ni] = __builtin_amdgcn_mfma_f32_16x16x32_bf16(
                        af[mi], bv[ni], acc[mi][ni], 0, 0, 0);
        }
    }

    // epilogue: C/D layout col = lane&15, row = quad*4 + reg
    float bev[4];
#pragma unroll
    for (int ni = 0; ni < 4; ++ni)
        bev[ni] = be[bn * TN + wc * 64 + ni * 16 + l15];

#pragma unroll
    for (int mi = 0; mi < 4; ++mi) {
        const int grow = bm * TM + wr * 64 + mi * 16 + quad * 4;
#pragma unroll
        for (int ni = 0; ni < 4; ++ni) {
            const int gcol = bn * TN + wc * 64 + ni * 16 + l15;
            float* po = out + (size_t)grow * OUT + gcol;
#pragma unroll
            for (int r = 0; r < 4; ++r)
                po[(size_t)r * OUT] = acc[mi][ni][r] + bev[ni];
        }
    }
}

extern "C" void kernel_launch(void* const* d_in, const int* in_sizes, int n_in,
                              void* d_out, int out_size, void* d_ws, size_t ws_size,
                              hipStream_t stream) {
    const float* x    = (const float*)d_in[0];   // [8192,1024]
    const float* W    = (const float*)d_in[1];   // [1024,1024]
    const float* C    = (const float*)d_in[2];   // [1024,1024,4]
    const float* bias = (const float*)d_in[3];   // [1024]
    float* out = (float*)d_out;

    unsigned short* Bb = (unsigned short*)d_ws;             // 8 MB
    float*          be = (float*)(Bb + (size_t)OUT * KDIM); // 4 KB

    prep_w<<<dim3(OUT), dim3(256), 0, stream>>>(W, C, bias, Bb, be);

    gemm_kan<<<dim3(512), dim3(256), 0, stream>>>(x, Bb, be, out);
}